// Round 1
// 93.404 us; speedup vs baseline: 1.0141x; 1.0141x over previous
//
#include <hip/hip_runtime.h>

// EntityRepr: gather spans -> mention means -> entity means + mask.
// B=32, L=512, H=768, E=32, M=8, S=4.
// Outputs concatenated fp32: entity [B,E,H] | mentions [B,E,M,H] | mask [B,E,M].
//
// Round 4 -> 5: same block/grid/XCD-swizzle structure. Changes:
//  - each mention's 4 span indices loaded as one dwordx4 (v4i) instead of
//    4 scalar int loads (4x fewer idx VMEM instrs, one latency event)
//  - all 8 gather loads issued before any arithmetic consumes them
//    (collapses two serial idx->gather latency stages into one)
//  - mask store moved ahead of the block barrier so it overlaps the reduce

#define B_  32
#define L_  512
#define H_  768
#define E_  32
#define M_  8
#define S_  4
#define H4_ (H_ / 4)              // 192 float4 per H-vector

#define ENT_ELEMS   (B_ * E_ * H_)          // 786432
#define MEN_ELEMS   (B_ * E_ * M_ * H_)     // 6291456
#define MEN_OFFSET  ENT_ELEMS               // 786432
#define MASK_OFFSET (ENT_ELEMS + MEN_ELEMS) // 7077888

typedef float v4f __attribute__((ext_vector_type(4)));
typedef int   v4i __attribute__((ext_vector_type(4)));

__global__ __launch_bounds__(768) void entity_repr_fused(
    const float* __restrict__ tok,   // [B, L, H]
    const int*   __restrict__ idx,   // [B, E, M, S]
    float*       __restrict__ out)
{
    // XCD swizzle: blockIdx round-robins over the 8 XCDs; give XCD k the
    // batches {k, k+8, k+16, k+24} in contiguous 32-block runs so the
    // resident blocks on one XCD touch <= 2 batch tables (3 MB < 4 MiB L2).
    const int s   = blockIdx.x;          // 0..1023
    const int xcd = s & 7;
    const int j   = s >> 3;              // 0..127
    const int b   = xcd + 8 * (j >> 5);  // batch
    const int e   = j & 31;              // entity
    const int be  = b * E_ + e;

    const int t    = threadIdx.x;        // 0..767
    const int mgrp = t / 192;            // 0..3 (mention group)
    const int col  = t - mgrp * 192;     // 0..191 (float4 column)

    const v4f* tb = (const v4f*)(tok) + (size_t)b * (L_ * H4_);
    const v4i* ip = (const v4i*)(idx) + (size_t)be * M_;   // one v4i per mention (S_=4)

    v4f* men_out = (v4f*)(out + MEN_OFFSET) + (size_t)be * (M_ * H4_);

    // Both mentions' span indices: two dwordx4 loads, issued back to back.
    const v4i ia = ip[mgrp];             // mention m = mgrp
    const v4i ib = ip[mgrp + 4];         // mention m = mgrp + 4

    // Issue all 8 gathers before consuming any (single latency stage;
    // 8 independent 1 KiB/wave loads in flight per wave).
    const v4f a0 = tb[(size_t)ia[0] * H4_ + col];
    const v4f a1 = tb[(size_t)ia[1] * H4_ + col];
    const v4f a2 = tb[(size_t)ia[2] * H4_ + col];
    const v4f a3 = tb[(size_t)ia[3] * H4_ + col];
    const v4f b0 = tb[(size_t)ib[0] * H4_ + col];
    const v4f b1 = tb[(size_t)ib[1] * H4_ + col];
    const v4f b2 = tb[(size_t)ib[2] * H4_ + col];
    const v4f b3 = tb[(size_t)ib[3] * H4_ + col];

    const v4f mna = (a0 + a1 + a2 + a3) * 0.25f;
    const v4f mnb = (b0 + b1 + b2 + b3) * 0.25f;

    __builtin_nontemporal_store(mna, &men_out[(size_t)mgrp * H4_ + col]);
    __builtin_nontemporal_store(mnb, &men_out[(size_t)(mgrp + 4) * H4_ + col]);

    // Mask store overlaps the LDS reduce (independent of it).
    if (t < M_) {
        __builtin_nontemporal_store(1.0f, &out[MASK_OFFSET + (size_t)be * M_ + t]);
    }

    // Block reduce across the 4 mention groups per column.
    __shared__ v4f red[4][H4_];          // 12 KB
    red[mgrp][col] = mna + mnb;
    __syncthreads();

    if (mgrp == 0) {
        const v4f r = (red[0][col] + red[1][col] + red[2][col] + red[3][col])
                      * (1.0f / M_);
        __builtin_nontemporal_store(r, &((v4f*)out)[(size_t)be * H4_ + col]);
    }
}

extern "C" void kernel_launch(void* const* d_in, const int* in_sizes, int n_in,
                              void* d_out, int out_size, void* d_ws, size_t ws_size,
                              hipStream_t stream) {
    const float* tok = (const float*)d_in[0];
    const int*   idx = (const int*)d_in[1];
    float*       out = (float*)d_out;

    entity_repr_fused<<<dim3(B_ * E_), dim3(768), 0, stream>>>(tok, idx, out);
}